// Round 3
// baseline (144.054 us; speedup 1.0000x reference)
//
#include <hip/hip_runtime.h>
#include <hip/hip_cooperative_groups.h>

namespace cg = cooperative_groups;

// HEGN loss: L_reg + bidirectional chamfer(x, y).  B=8, N=M=4096.
// Single cooperative kernel: phase 1 (chunked partial mins) -> grid.sync()
// -> phase 2 (cross-chunk min + sum + L_reg).
#define BB 8
#define NN 4096
#define MC 512                    // reference points staged per chunk
#define NCHUNK (NN / MC)          // 8
#define KPT 4                     // query points per thread
#define TPB 256
#define PTS_PER_BLOCK (TPB * KPT) // 1024
#define GRID_X (NN / PTS_PER_BLOCK) // 4; grid = (4, 8, 16) = 512 blocks
#define NPTS (2 * BB * NN)        // 65536 (both directions)

// ws layout: partial[c][zb][p]  c in [0,8), zb in [0,16), p in [0,4096) -> 2 MB

__global__ __launch_bounds__(TPB) void hegn_fused(
    const float* __restrict__ X, const float* __restrict__ Y,
    const float* __restrict__ R, const float* __restrict__ S,
    const float* __restrict__ t, const float* __restrict__ Rgt,
    const float* __restrict__ Sgt, const float* __restrict__ tgt,
    float* __restrict__ partial, float* __restrict__ out) {
  __shared__ float4 ly[MC];       // (-2*y0, -2*y1, -2*y2, |y|^2); 8 KB
  const int tid = threadIdx.x;
  const int zb  = blockIdx.z;     // (dir<<3) | b
  const int b   = zb & (BB - 1);
  const int dir = zb >> 3;
  const float* pts  = dir ? (Y + b * NN * 3) : (X + b * NN * 3);
  const float* refs = dir ? (X + b * NN * 3) : (Y + b * NN * 3);
  const int c = blockIdx.y;

  // out zeroed before grid.sync(); all atomics happen after the sync.
  if (tid == 0 && blockIdx.x == 0 && blockIdx.y == 0 && blockIdx.z == 0)
    *out = 0.0f;

#pragma unroll
  for (int i = 0; i < MC / TPB; i++) {     // 2 staging iterations
    const int jj = i * TPB + tid;
    const int j = c * MC + jj;
    const float a0 = refs[j * 3 + 0];
    const float a1 = refs[j * 3 + 1];
    const float a2 = refs[j * 3 + 2];
    ly[jj] = make_float4(-2.0f * a0, -2.0f * a1, -2.0f * a2,
                         a0 * a0 + a1 * a1 + a2 * a2);
  }
  __syncthreads();

  float px[KPT], py[KPT], pz[KPT], m[KPT];
  const int p0 = blockIdx.x * PTS_PER_BLOCK + tid;
#pragma unroll
  for (int k = 0; k < KPT; k++) {
    const int p = p0 + k * TPB;
    px[k] = pts[p * 3 + 0];
    py[k] = pts[p * 3 + 1];
    pz[k] = pts[p * 3 + 2];
    m[k] = 1e30f;
  }

  // min over chunk of (|y|^2 - 2 x.y); |x|^2 added after the loop.
  // 4-ref body, next body's LDS reads issued one body ahead.
  // min3 pairing: 2 x v_min3_f32 per (4 refs x query).
#define CHAMFER_BODY(w0, w1, w2, w3)                                           \
  _Pragma("unroll") for (int k = 0; k < KPT; k++) {                            \
    const float s0 =                                                           \
        fmaf(px[k], w0.x, fmaf(py[k], w0.y, fmaf(pz[k], w0.z, w0.w)));         \
    const float s1 =                                                           \
        fmaf(px[k], w1.x, fmaf(py[k], w1.y, fmaf(pz[k], w1.z, w1.w)));         \
    const float s2 =                                                           \
        fmaf(px[k], w2.x, fmaf(py[k], w2.y, fmaf(pz[k], w2.z, w2.w)));         \
    const float s3 =                                                           \
        fmaf(px[k], w3.x, fmaf(py[k], w3.y, fmaf(pz[k], w3.z, w3.w)));         \
    m[k] = fminf(fminf(s0, s1), m[k]);  /* -> v_min3_f32 */                    \
    m[k] = fminf(fminf(s2, s3), m[k]);  /* -> v_min3_f32 */                    \
  }

  float4 w0 = ly[0], w1 = ly[1], w2 = ly[2], w3 = ly[3];
#pragma unroll 2
  for (int j = 0; j < MC - 4; j += 4) {
    const float4 n0 = ly[j + 4];
    const float4 n1 = ly[j + 5];
    const float4 n2 = ly[j + 6];
    const float4 n3 = ly[j + 7];
    CHAMFER_BODY(w0, w1, w2, w3)
    w0 = n0; w1 = n1; w2 = n2; w3 = n3;
  }
  CHAMFER_BODY(w0, w1, w2, w3)
#undef CHAMFER_BODY

#pragma unroll
  for (int k = 0; k < KPT; k++) {
    const int p = p0 + k * TPB;
    const float pn = px[k] * px[k] + py[k] * py[k] + pz[k] * pz[k];
    partial[(c * (2 * BB) + zb) * NN + p] = m[k] + pn;
  }

  cg::this_grid().sync();

  // ---- Phase 2: blocks 0..255 reduce; others exit. ----
  const int bid = blockIdx.x + GRID_X * (blockIdx.y + NCHUNK * blockIdx.z);
  if (bid >= 256) return;

  const int q = bid * 256 + tid;          // covers NPTS = 65536
  float mn = 1e30f;
#pragma unroll
  for (int cc = 0; cc < NCHUNK; cc++)
    mn = fminf(mn, partial[cc * NPTS + q]);
  float s = mn;
  for (int o = 32; o > 0; o >>= 1) s += __shfl_down(s, o);
  __shared__ float wsum[4];
  if ((tid & 63) == 0) wsum[tid >> 6] = s;
  __syncthreads();
  if (tid == 0) {
    const float bs = wsum[0] + wsum[1] + wsum[2] + wsum[3];
    atomicAdd(out, bs * (1.0f / (float)(BB * NN)));
  }

  if (bid == 0) {
    float v = 0.0f;
    if (tid < 72) {                       // R @ R_gt^T - I, squared
      const int bb = tid / 9, ik = tid % 9, i = ik / 3, k = ik % 3;
      const float* Rb = R + bb * 9;
      const float* Gb = Rgt + bb * 9;
      float d = Rb[i * 3 + 0] * Gb[k * 3 + 0] +
                Rb[i * 3 + 1] * Gb[k * 3 + 1] +
                Rb[i * 3 + 2] * Gb[k * 3 + 2];
      d -= (i == k) ? 1.0f : 0.0f;
      v = d * d;
    } else if (tid < 96) {                // (S - S_gt)^2
      const int i = tid - 72;
      const float d = S[i] - Sgt[i];
      v = d * d;
    } else if (tid < 120) {               // (t - t_gt)^2
      const int i = tid - 96;
      const float d = t[i] - tgt[i];
      v = d * d;
    }
    for (int o = 32; o > 0; o >>= 1) v += __shfl_down(v, o);
    __shared__ float rsum[4];
    if ((tid & 63) == 0) rsum[tid >> 6] = v;
    __syncthreads();
    if (tid == 0) atomicAdd(out, rsum[0] + rsum[1] + rsum[2] + rsum[3]);
  }
}

extern "C" void kernel_launch(void* const* d_in, const int* in_sizes, int n_in,
                              void* d_out, int out_size, void* d_ws, size_t ws_size,
                              hipStream_t stream) {
  const float* X   = (const float*)d_in[0];
  const float* Y   = (const float*)d_in[1];
  const float* R   = (const float*)d_in[2];
  const float* S   = (const float*)d_in[3];
  const float* t   = (const float*)d_in[4];
  const float* Rgt = (const float*)d_in[5];
  const float* Sgt = (const float*)d_in[6];
  const float* tgt = (const float*)d_in[7];

  float* partial = (float*)d_ws;
  float* out     = (float*)d_out;

  dim3 gA(GRID_X, NCHUNK, 2 * BB);   // (4, 8, 16) = 512 blocks, co-resident
  void* args[] = {(void*)&X, (void*)&Y, (void*)&R, (void*)&S, (void*)&t,
                  (void*)&Rgt, (void*)&Sgt, (void*)&tgt,
                  (void*)&partial, (void*)&out};
  hipLaunchCooperativeKernel((void*)hegn_fused, gA, dim3(TPB, 1, 1), args, 0,
                             stream);
}

// Round 4
// 96.593 us; speedup vs baseline: 1.4914x; 1.4914x over previous
//
#include <hip/hip_runtime.h>

// HEGN loss: L_reg + bidirectional chamfer(x, y).  B=8, N=M=4096.
// Two kernels (plain launches; cooperative fuse measured +52us, reverted).
// Phase 1 tuned for stall coverage: KPT=8 (112 VALU / 4 ds_read body)
// AND 4 waves/SIMD (1024 blocks) via NCHUNK=32.
#define BB 8
#define NN 4096
#define MC 128                    // reference points staged per chunk
#define NCHUNK (NN / MC)          // 32
#define KPT 8                     // query points per thread
#define TPB 256
#define PTS_PER_BLOCK (TPB * KPT) // 2048
#define GRID_X (NN / PTS_PER_BLOCK) // 2; grid = (2, 32, 16) = 1024 blocks
#define NPTS (2 * BB * NN)        // 65536 (both directions)

// ws layout: partial[c][zb][p]  c in [0,32), zb in [0,16), p in [0,4096) -> 8 MB

__global__ __launch_bounds__(TPB) void chamfer_partial(
    const float* __restrict__ X, const float* __restrict__ Y,
    float* __restrict__ partial, float* __restrict__ out) {
  __shared__ float4 ly[MC];       // (-2*y0, -2*y1, -2*y2, |y|^2); 2 KB
  const int tid = threadIdx.x;
  const int zb  = blockIdx.z;     // (dir<<3) | b
  const int b   = zb & (BB - 1);
  const int dir = zb >> 3;
  const float* pts  = dir ? (Y + b * NN * 3) : (X + b * NN * 3);
  const float* refs = dir ? (X + b * NN * 3) : (Y + b * NN * 3);
  const int c = blockIdx.y;

  // Replaces the 4-byte hipMemsetAsync dispatch. Safe: chamfer_reduce only
  // touches out after this kernel fully completes (stream ordering).
  if (tid == 0 && blockIdx.x == 0 && blockIdx.y == 0 && blockIdx.z == 0)
    *out = 0.0f;

  if (tid < MC) {                 // MC == 128: half the threads stage
    const int j = c * MC + tid;
    const float a0 = refs[j * 3 + 0];
    const float a1 = refs[j * 3 + 1];
    const float a2 = refs[j * 3 + 2];
    ly[tid] = make_float4(-2.0f * a0, -2.0f * a1, -2.0f * a2,
                          a0 * a0 + a1 * a1 + a2 * a2);
  }
  __syncthreads();

  float px[KPT], py[KPT], pz[KPT], m[KPT];
  const int p0 = blockIdx.x * PTS_PER_BLOCK + tid;
#pragma unroll
  for (int k = 0; k < KPT; k++) {
    const int p = p0 + k * TPB;
    px[k] = pts[p * 3 + 0];
    py[k] = pts[p * 3 + 1];
    pz[k] = pts[p * 3 + 2];
    m[k] = 1e30f;
  }

  // min over chunk of (|y|^2 - 2 x.y); |x|^2 added after the loop.
  // 4-ref body x KPT=8 queries: 112 VALU (~224 issue-cy) per 4 uniform
  // ds_read_b128 (issued one body ahead) -> LDS latency fully covered.
#define CHAMFER_BODY(w0, w1, w2, w3)                                           \
  _Pragma("unroll") for (int k = 0; k < KPT; k++) {                            \
    const float s0 =                                                           \
        fmaf(px[k], w0.x, fmaf(py[k], w0.y, fmaf(pz[k], w0.z, w0.w)));         \
    const float s1 =                                                           \
        fmaf(px[k], w1.x, fmaf(py[k], w1.y, fmaf(pz[k], w1.z, w1.w)));         \
    const float s2 =                                                           \
        fmaf(px[k], w2.x, fmaf(py[k], w2.y, fmaf(pz[k], w2.z, w2.w)));         \
    const float s3 =                                                           \
        fmaf(px[k], w3.x, fmaf(py[k], w3.y, fmaf(pz[k], w3.z, w3.w)));         \
    m[k] = fminf(fminf(s0, s1), m[k]);  /* -> v_min3_f32 */                    \
    m[k] = fminf(fminf(s2, s3), m[k]);  /* -> v_min3_f32 */                    \
  }

  float4 w0 = ly[0], w1 = ly[1], w2 = ly[2], w3 = ly[3];
#pragma unroll 2
  for (int j = 0; j < MC - 4; j += 4) {
    const float4 n0 = ly[j + 4];
    const float4 n1 = ly[j + 5];
    const float4 n2 = ly[j + 6];
    const float4 n3 = ly[j + 7];
    CHAMFER_BODY(w0, w1, w2, w3)
    w0 = n0; w1 = n1; w2 = n2; w3 = n3;
  }
  CHAMFER_BODY(w0, w1, w2, w3)
#undef CHAMFER_BODY

#pragma unroll
  for (int k = 0; k < KPT; k++) {
    const int p = p0 + k * TPB;
    const float pn = px[k] * px[k] + py[k] * py[k] + pz[k] * pz[k];
    partial[(c * (2 * BB) + zb) * NN + p] = m[k] + pn;
  }
}

// Min across chunks, block-sum, 1 atomic per block into out (zeroed by
// chamfer_partial). Block 0 also adds L_reg. 256 blocks x 1 q/thread:
// all 32 chunk loads independent -> latency-bound time minimized.
__global__ __launch_bounds__(256) void chamfer_reduce(
    const float* __restrict__ partial,
    const float* __restrict__ R, const float* __restrict__ S,
    const float* __restrict__ t, const float* __restrict__ Rgt,
    const float* __restrict__ Sgt, const float* __restrict__ tgt,
    float* __restrict__ out) {
  const int tid = threadIdx.x;
  const int q = blockIdx.x * 256 + tid;   // 256 blocks cover NPTS
  float m = 1e30f;
#pragma unroll
  for (int c = 0; c < NCHUNK; c++)
    m = fminf(m, partial[c * NPTS + q]);
  float s = m;
  for (int o = 32; o > 0; o >>= 1) s += __shfl_down(s, o);
  __shared__ float wsum[4];
  if ((tid & 63) == 0) wsum[tid >> 6] = s;
  __syncthreads();
  if (tid == 0) {
    const float bs = wsum[0] + wsum[1] + wsum[2] + wsum[3];
    atomicAdd(out, bs * (1.0f / (float)(BB * NN)));
  }

  if (blockIdx.x == 0) {
    float v = 0.0f;
    if (tid < 72) {                       // R @ R_gt^T - I, squared
      const int b = tid / 9, ik = tid % 9, i = ik / 3, k = ik % 3;
      const float* Rb = R + b * 9;
      const float* Gb = Rgt + b * 9;
      float d = Rb[i * 3 + 0] * Gb[k * 3 + 0] +
                Rb[i * 3 + 1] * Gb[k * 3 + 1] +
                Rb[i * 3 + 2] * Gb[k * 3 + 2];
      d -= (i == k) ? 1.0f : 0.0f;
      v = d * d;
    } else if (tid < 96) {                // (S - S_gt)^2
      const int i = tid - 72;
      const float d = S[i] - Sgt[i];
      v = d * d;
    } else if (tid < 120) {               // (t - t_gt)^2
      const int i = tid - 96;
      const float d = t[i] - tgt[i];
      v = d * d;
    }
    for (int o = 32; o > 0; o >>= 1) v += __shfl_down(v, o);
    __shared__ float rsum[4];
    if ((tid & 63) == 0) rsum[tid >> 6] = v;
    __syncthreads();
    if (tid == 0) atomicAdd(out, rsum[0] + rsum[1] + rsum[2] + rsum[3]);
  }
}

extern "C" void kernel_launch(void* const* d_in, const int* in_sizes, int n_in,
                              void* d_out, int out_size, void* d_ws, size_t ws_size,
                              hipStream_t stream) {
  const float* X   = (const float*)d_in[0];
  const float* Y   = (const float*)d_in[1];
  const float* R   = (const float*)d_in[2];
  const float* S   = (const float*)d_in[3];
  const float* t   = (const float*)d_in[4];
  const float* Rgt = (const float*)d_in[5];
  const float* Sgt = (const float*)d_in[6];
  const float* tgt = (const float*)d_in[7];

  float* partial = (float*)d_ws;
  float* out     = (float*)d_out;

  dim3 gA(GRID_X, NCHUNK, 2 * BB);   // (2, 32, 16) = 1024 blocks
  chamfer_partial<<<gA, TPB, 0, stream>>>(X, Y, partial, out);

  chamfer_reduce<<<NPTS / 256, 256, 0, stream>>>(partial, R, S, t, Rgt, Sgt, tgt, out);
}

// Round 5
// 94.173 us; speedup vs baseline: 1.5297x; 1.0257x over previous
//
#include <hip/hip_runtime.h>

// HEGN loss: L_reg + bidirectional chamfer(x, y).  B=8, N=M=4096.
// Phase 1: refs staged in LDS; inner loop is an inline-asm software pipeline
// (issue next body's ds_read_b128 quad -> run current body's VALU ->
//  s_waitcnt lgkmcnt(0) + sched_barrier(0)).  The compiler provably deletes
// source-level prefetch here (R3: VGPR_Count=28), so the pipeline is forced.
#define BB 8
#define NN 4096
#define MC 256                    // reference points staged per chunk
#define NBODY (MC / 4)            // 64 4-ref bodies per chunk
#define NCHUNK (NN / MC)          // 16
#define KPT 8                     // query points per thread
#define TPB 256
#define PTS_PER_BLOCK (TPB * KPT) // 2048
#define GRID_X (NN / PTS_PER_BLOCK) // 2; grid = (2, 16, 16) = 512 blocks
#define NPTS (2 * BB * NN)        // 65536 (both directions)

typedef float f32x4 __attribute__((ext_vector_type(4)));

// Issue 4 ds_read_b128 for body `bodyidx` (64B apart, 16B each).
#define ISSUE4(A0, A1, A2, A3, bodyidx)                                        \
  do {                                                                         \
    const unsigned _a = lbase + (unsigned)(bodyidx) * 64u;                     \
    asm volatile("ds_read_b128 %0, %4 offset:0\n\t"                            \
                 "ds_read_b128 %1, %4 offset:16\n\t"                           \
                 "ds_read_b128 %2, %4 offset:32\n\t"                           \
                 "ds_read_b128 %3, %4 offset:48"                               \
                 : "=&v"(A0), "=&v"(A1), "=&v"(A2), "=&v"(A3)                  \
                 : "v"(_a));                                                   \
  } while (0)

// Rule #18: lgkmcnt(0) then sched_barrier(0) so no consumer is hoisted above.
#define WAIT_LDS()                                                             \
  do {                                                                         \
    asm volatile("s_waitcnt lgkmcnt(0)" ::: "memory");                         \
    __builtin_amdgcn_sched_barrier(0);                                         \
  } while (0)

// 4 refs x KPT queries: 12 fma + 2 min3 per query (112 VALU at KPT=8).
#define CHAMFER_BODY(w0, w1, w2, w3)                                           \
  _Pragma("unroll") for (int k = 0; k < KPT; k++) {                            \
    const float s0 =                                                           \
        fmaf(px[k], w0[0], fmaf(py[k], w0[1], fmaf(pz[k], w0[2], w0[3])));     \
    const float s1 =                                                           \
        fmaf(px[k], w1[0], fmaf(py[k], w1[1], fmaf(pz[k], w1[2], w1[3])));     \
    const float s2 =                                                           \
        fmaf(px[k], w2[0], fmaf(py[k], w2[1], fmaf(pz[k], w2[2], w2[3])));     \
    const float s3 =                                                           \
        fmaf(px[k], w3[0], fmaf(py[k], w3[1], fmaf(pz[k], w3[2], w3[3])));     \
    m[k] = fminf(fminf(s0, s1), m[k]); /* -> v_min3_f32 */                     \
    m[k] = fminf(fminf(s2, s3), m[k]); /* -> v_min3_f32 */                     \
  }

// ws layout: partial[c][zb][p]  c in [0,16), zb in [0,16), p in [0,4096) -> 4 MB

__global__ __launch_bounds__(TPB) void chamfer_partial(
    const float* __restrict__ X, const float* __restrict__ Y,
    float* __restrict__ partial, float* __restrict__ out) {
  __shared__ f32x4 ly[MC];        // (-2*y0, -2*y1, -2*y2, |y|^2); 4 KB
  const int tid = threadIdx.x;
  const int zb  = blockIdx.z;     // (dir<<3) | b
  const int b   = zb & (BB - 1);
  const int dir = zb >> 3;
  const float* pts  = dir ? (Y + b * NN * 3) : (X + b * NN * 3);
  const float* refs = dir ? (X + b * NN * 3) : (Y + b * NN * 3);
  const int c = blockIdx.y;

  // Replaces the 4-byte hipMemsetAsync dispatch. Safe: chamfer_reduce only
  // touches out after this kernel fully completes (stream ordering).
  if (tid == 0 && blockIdx.x == 0 && blockIdx.y == 0 && blockIdx.z == 0)
    *out = 0.0f;

  {
    const int j = c * MC + tid;   // MC == TPB: one staging iteration
    const float a0 = refs[j * 3 + 0];
    const float a1 = refs[j * 3 + 1];
    const float a2 = refs[j * 3 + 2];
    ly[tid] = (f32x4){-2.0f * a0, -2.0f * a1, -2.0f * a2,
                      a0 * a0 + a1 * a1 + a2 * a2};
  }
  __syncthreads();

  float px[KPT], py[KPT], pz[KPT], m[KPT];
  const int p0 = blockIdx.x * PTS_PER_BLOCK + tid;
#pragma unroll
  for (int k = 0; k < KPT; k++) {
    const int p = p0 + k * TPB;
    px[k] = pts[p * 3 + 0];
    py[k] = pts[p * 3 + 1];
    pz[k] = pts[p * 3 + 2];
    m[k] = 1e30f;
  }

  const unsigned lbase = (unsigned)(uintptr_t)&ly[0];
  f32x4 a0, a1, a2, a3, b0, b1, b2, b3;

  // Software pipeline over 64 bodies: A/B register sets alternate.
  ISSUE4(a0, a1, a2, a3, 0);
  WAIT_LDS();
#pragma unroll 1
  for (int bj = 0; bj < NBODY - 2; bj += 2) {
    ISSUE4(b0, b1, b2, b3, bj + 1);
    CHAMFER_BODY(a0, a1, a2, a3)
    WAIT_LDS();
    ISSUE4(a0, a1, a2, a3, bj + 2);
    CHAMFER_BODY(b0, b1, b2, b3)
    WAIT_LDS();
  }
  ISSUE4(b0, b1, b2, b3, NBODY - 1);
  CHAMFER_BODY(a0, a1, a2, a3)   // body NBODY-2
  WAIT_LDS();
  CHAMFER_BODY(b0, b1, b2, b3)   // body NBODY-1

#pragma unroll
  for (int k = 0; k < KPT; k++) {
    const int p = p0 + k * TPB;
    const float pn = px[k] * px[k] + py[k] * py[k] + pz[k] * pz[k];
    partial[(c * (2 * BB) + zb) * NN + p] = m[k] + pn;
  }
}

// Min across chunks, block-sum, 1 atomic per block into out (zeroed by
// chamfer_partial). Block 0 also adds L_reg. 256 blocks x 1 q/thread:
// all 16 chunk loads independent -> latency-bound time minimized.
__global__ __launch_bounds__(256) void chamfer_reduce(
    const float* __restrict__ partial,
    const float* __restrict__ R, const float* __restrict__ S,
    const float* __restrict__ t, const float* __restrict__ Rgt,
    const float* __restrict__ Sgt, const float* __restrict__ tgt,
    float* __restrict__ out) {
  const int tid = threadIdx.x;
  const int q = blockIdx.x * 256 + tid;   // 256 blocks cover NPTS
  float m = 1e30f;
#pragma unroll
  for (int c = 0; c < NCHUNK; c++)
    m = fminf(m, partial[c * NPTS + q]);
  float s = m;
  for (int o = 32; o > 0; o >>= 1) s += __shfl_down(s, o);
  __shared__ float wsum[4];
  if ((tid & 63) == 0) wsum[tid >> 6] = s;
  __syncthreads();
  if (tid == 0) {
    const float bs = wsum[0] + wsum[1] + wsum[2] + wsum[3];
    atomicAdd(out, bs * (1.0f / (float)(BB * NN)));
  }

  if (blockIdx.x == 0) {
    float v = 0.0f;
    if (tid < 72) {                       // R @ R_gt^T - I, squared
      const int b = tid / 9, ik = tid % 9, i = ik / 3, k = ik % 3;
      const float* Rb = R + b * 9;
      const float* Gb = Rgt + b * 9;
      float d = Rb[i * 3 + 0] * Gb[k * 3 + 0] +
                Rb[i * 3 + 1] * Gb[k * 3 + 1] +
                Rb[i * 3 + 2] * Gb[k * 3 + 2];
      d -= (i == k) ? 1.0f : 0.0f;
      v = d * d;
    } else if (tid < 96) {                // (S - S_gt)^2
      const int i = tid - 72;
      const float d = S[i] - Sgt[i];
      v = d * d;
    } else if (tid < 120) {               // (t - t_gt)^2
      const int i = tid - 96;
      const float d = t[i] - tgt[i];
      v = d * d;
    }
    for (int o = 32; o > 0; o >>= 1) v += __shfl_down(v, o);
    __shared__ float rsum[4];
    if ((tid & 63) == 0) rsum[tid >> 6] = v;
    __syncthreads();
    if (tid == 0) atomicAdd(out, rsum[0] + rsum[1] + rsum[2] + rsum[3]);
  }
}

extern "C" void kernel_launch(void* const* d_in, const int* in_sizes, int n_in,
                              void* d_out, int out_size, void* d_ws, size_t ws_size,
                              hipStream_t stream) {
  const float* X   = (const float*)d_in[0];
  const float* Y   = (const float*)d_in[1];
  const float* R   = (const float*)d_in[2];
  const float* S   = (const float*)d_in[3];
  const float* t   = (const float*)d_in[4];
  const float* Rgt = (const float*)d_in[5];
  const float* Sgt = (const float*)d_in[6];
  const float* tgt = (const float*)d_in[7];

  float* partial = (float*)d_ws;
  float* out     = (float*)d_out;

  dim3 gA(GRID_X, NCHUNK, 2 * BB);   // (2, 16, 16) = 512 blocks
  chamfer_partial<<<gA, TPB, 0, stream>>>(X, Y, partial, out);

  chamfer_reduce<<<NPTS / 256, 256, 0, stream>>>(partial, R, S, t, Rgt, Sgt, tgt, out);
}